// Round 10
// baseline (398.887 us; speedup 1.0000x reference)
//
#include <hip/hip_runtime.h>
#include <math.h>

#define Tn   400
#define Bn   2
#define Sn   96000
#define NHh  128
#define NNn  513
#define NFFT 1024
#define HOPs 256
#define PADs 512
#define TS   376      // 1 + Sn/HOPs
#define LPn  97024    // NFFT + (TS-1)*HOPs
#define CUT  21600.0f // SR*0.45
#define DPI  3.14159265358979323846

__device__ __forceinline__ float sigmoidf_(float x){ return 1.0f/(1.0f+expf(-x)); }
__device__ __forceinline__ float softplusf_(float x){ return fmaxf(x,0.0f)+log1pf(expf(-fabsf(x))); }
__device__ __forceinline__ float fsigmoid_(float x){ return __fdividef(1.0f, 1.0f + __expf(-x)); }
__device__ __forceinline__ float ftanh_(float x){
  float e = __expf(fminf(fmaxf(2.0f*x, -30.0f), 30.0f));
  return __fdividef(e - 1.0f, e + 1.0f);
}

// ---- frame-rate MLP (blocks 0..799) + setup (block 800) + ola zero -------
__global__ void __launch_bounds__(128) k_frame1z(
    const float* f0, const int* vel,
    const float* Wp1, const float* bp1,
    const float* Wp2, const float* bp2,
    const float* Wih, const float* bih,
    float* gi, float4* olaz, float* fs, double* P) {
  int blk = blockIdx.x;
  int tid = threadIdx.x;
  if (blk >= Bn*Tn) {
    if (blk == Bn*Tn) {
      int b = tid;
      if (b < Bn) {
        const float* f = f0 + b*Tn;
        double sm = 0.0;
        for (int t=0;t<Tn;t++) sm += fmax((double)f[t], 20.0);
        float f0m = (float)(sm / (double)Tn);
        fs[b] = f0m;
        float midi = 69.0f + 12.0f * log2f(f0m/440.0f);
        fs[2+b] = 0.0008f * expf(-(midi-21.0f)*(1.0f/88.0f) * 2.302585093f);
        double* Pb = P + b*Tn;
        double acc = 0.0;
        for (int m=0;m<Tn;m++){ Pb[m] = acc; if (m < Tn-1) acc += (double)f[m] + (double)f[m+1]; }
        double Ctot = 120.0*((double)f[0] + Pb[Tn-1] + (double)f[Tn-1]);
        double fupmean = Ctot / (double)Sn;
        int cnt = 0;
        for (int k=1;k<=NHh;k++) if ((float)k * (float)fupmean < CUT) cnt++;
        if (cnt < 1) cnt = 1;
        fs[4+b] = (float)cnt;
        fs[6+b] = 0.0f;            // atomic accumulator for k_heads
      }
    } else {
      int base = (blk - (Bn*Tn+1))*512 + tid;
      #pragma unroll
      for (int r=0;r<4;r++) {
        int idx = base + r*128;
        if (idx < 97024) olaz[idx] = make_float4(0.f,0.f,0.f,0.f);
      }
    }
    return;
  }
  int b = blk / Tn, t = blk % Tn;
  __shared__ float x[72];
  __shared__ float y1[128];
  __shared__ float y2[128];
  if (tid < 72) {
    if (tid < 64) {
      float fv = f0[b*Tn+t];
      float fsv = fmaxf(fv, 20.0f);
      float fn = (logf(fsv) - 2.99573227355399f) * (1.0f/5.52146091786225f);
      fn = fminf(fmaxf(fn,0.0f),1.0f);
      int j = (tid>>1) + 1;
      float ang = (float)DPI * (float)j * fn;
      x[tid] = (tid & 1) ? cosf(ang) : sinf(ang);
    } else {
      int i = tid - 64;
      float vn = fminf(fmaxf((float)vel[b]*(1.0f/7.0f),0.0f),1.0f);
      int j = (i>>1)+1;
      float ang = (float)DPI * (float)j * vn;
      x[tid] = (i & 1) ? cosf(ang) : sinf(ang);
    }
  }
  __syncthreads();
  {
    float a = bp1[tid];
    #pragma unroll 8
    for (int i=0;i<72;i++) a += x[i]*Wp1[i*128+tid];
    y1[tid] = fmaxf(a,0.0f);
  }
  __syncthreads();
  {
    float a = bp2[tid];
    #pragma unroll 8
    for (int i=0;i<128;i++) a += y1[i]*Wp2[i*128+tid];
    y2[tid] = fmaxf(a,0.0f);
  }
  __syncthreads();
  float* gout = gi + ((size_t)b*Tn + t)*192;
  for (int g = tid; g < 192; g += 128) {
    float s = bih[g];
    const float* wr = Wih + g*128;
    #pragma unroll 8
    for (int d=0; d<128; d++) s += y2[d]*wr[d];
    gout[g] = s;
  }
}

// ------ fused GRU (blocks 0,1) + forward noise FFT (blocks 2..1505) -------
// Evolution of the measured-best R6/R8 phase-split (173.9us):
//  - 13 waves -> 7: 6 matvec waves (2-way K-split, 8 float4 = 32 weight
//    VGPRs; residency proven by R7's VGPR=44 + flat FETCH) + 1 gate wave.
//    Halves barrier participants + VALU contention.
//  - gi/hist chunk depth 8 -> 16: the gate wave's chunk-boundary global
//    ops are vmcnt(0)-drained at the next s_barrier (~900cyc); deeper
//    chunking halves that amortized cost (~110 -> ~55 cyc/step).
// R7 lesson stands: no redundant gate computation, no readlane matvec.
__global__ void __launch_bounds__(448, 1) k_grufft(
    const float* __restrict__ gi, const float* __restrict__ Whh,
    const float* __restrict__ bhh, float* __restrict__ hsout,
    const float* __restrict__ noiseL, const float* __restrict__ noiseR,
    float2* __restrict__ spec) {
  __shared__ float h[64];
  __shared__ float sp[384];               // p*192 + row
  __shared__ float re[1024], im[1024];
  __shared__ float twc[512], tws[512];
  __shared__ float wdw[1024];
  int j = threadIdx.x;

  if (blockIdx.x >= 2) {
    // ---------------- forward FFT branch (256 working threads) ----------
    if (j >= 256) return;                 // waves 4..6 exit whole
    int idx = blockIdx.x - 2;
    int sig = idx / TS, t = idx % TS;
    int b = sig >> 1, c = sig & 1;
    const float* noise = (c==0 ? noiseL : noiseR) + (size_t)b*Sn;
    int tid = j;
    for (int q=tid; q<512; q+=256) {
      float ang = (float)(2.0*DPI) * (float)q * (1.0f/1024.0f);
      twc[q] = cosf(ang); tws[q] = sinf(ang);
    }
    for (int i=tid; i<1024; i+=256)
      wdw[i] = 0.5f - 0.5f*cosf((float)(2.0*DPI)*(float)i*(1.0f/1024.0f));
    __syncthreads();
    for (int i=tid;i<1024;i+=256) {
      int q = t*HOPs + i - PADs;
      if (q < 0) q = -q;
      if (q >= Sn) q = 2*Sn - 2 - q;
      float v = noise[q]*wdw[i];
      int br = (int)(__brev((unsigned)i) >> 22);
      re[br] = v; im[br] = 0.0f;
    }
    __syncthreads();
    for (int st=1; st<=10; st++) {
      int half = 1<<(st-1);
      #pragma unroll
      for (int w=0;w<2;w++) {
        int bid = tid + w*256;
        int pos = bid & (half-1);
        int i0 = ((bid >> (st-1)) << st) + pos;
        int i1 = i0 + half;
        int q = pos << (10-st);
        float cr = twc[q], ci = -tws[q];
        float xr = re[i1], xi = im[i1];
        float tr = cr*xr - ci*xi, ti = cr*xi + ci*xr;
        float ar = re[i0], ai = im[i0];
        re[i1] = ar - tr; im[i1] = ai - ti;
        re[i0] = ar + tr; im[i0] = ai + ti;
      }
      __syncthreads();
    }
    float2* so = spec + ((size_t)sig*TS + t)*NNn;
    for (int k=tid;k<=512;k+=256) so[k] = make_float2(re[k], im[k]);
    return;
  }

  // ---------------- GRU branch (448 threads = 7 waves) ------------------
  int b = blockIdx.x;
  const float* gib = gi + (size_t)b*Tn*192;
  float* hb_ = hsout + (size_t)b*Tn*64;
  int wv = j >> 6, lane = j & 63;
  int p = wv & 1;                 // K-half
  int row = (wv >> 1)*64 + lane;  // 0..191
  float4 w0,w1,w2,w3,w4,w5,w6,w7;
  if (wv < 6) {
    const float4* W4 = (const float4*)(Whh + (size_t)row*64 + p*32);
    w0=W4[0]; w1=W4[1]; w2=W4[2]; w3=W4[3];
    w4=W4[4]; w5=W4[5]; w6=W4[6]; w7=W4[7];
    if (j < 64) h[j] = 0.0f;
  }
  float hu = 0.0f, br=0.f, bz=0.f, bn=0.f;
  float ga[16], gz_[16], gn_[16], hist[16];
  if (wv == 6) {
    br = bhh[lane]; bz = bhh[64+lane]; bn = bhh[128+lane];
    #pragma unroll
    for (int i=0;i<16;i++) {
      ga[i]  = gib[(size_t)i*192 + lane];
      gz_[i] = gib[(size_t)i*192 + 64 + lane];
      gn_[i] = gib[(size_t)i*192 + 128 + lane];
    }
  }
  __syncthreads();

  for (int c=0;c<25;c++) {
    #pragma unroll
    for (int i=0;i<16;i++) {
      if (wv < 6) {
        const float4* h4 = (const float4*)h;
        float4 x0=h4[p*8+0], x1=h4[p*8+1], x2=h4[p*8+2], x3=h4[p*8+3];
        float4 x4=h4[p*8+4], x5=h4[p*8+5], x6=h4[p*8+6], x7=h4[p*8+7];
        float a0,a1,a2,a3;
        a0 = w0.x*x0.x; a1 = w0.y*x0.y; a2 = w0.z*x0.z; a3 = w0.w*x0.w;
        a0 = fmaf(w1.x,x1.x,a0); a1 = fmaf(w1.y,x1.y,a1);
        a2 = fmaf(w1.z,x1.z,a2); a3 = fmaf(w1.w,x1.w,a3);
        a0 = fmaf(w2.x,x2.x,a0); a1 = fmaf(w2.y,x2.y,a1);
        a2 = fmaf(w2.z,x2.z,a2); a3 = fmaf(w2.w,x2.w,a3);
        a0 = fmaf(w3.x,x3.x,a0); a1 = fmaf(w3.y,x3.y,a1);
        a2 = fmaf(w3.z,x3.z,a2); a3 = fmaf(w3.w,x3.w,a3);
        a0 = fmaf(w4.x,x4.x,a0); a1 = fmaf(w4.y,x4.y,a1);
        a2 = fmaf(w4.z,x4.z,a2); a3 = fmaf(w4.w,x4.w,a3);
        a0 = fmaf(w5.x,x5.x,a0); a1 = fmaf(w5.y,x5.y,a1);
        a2 = fmaf(w5.z,x5.z,a2); a3 = fmaf(w5.w,x5.w,a3);
        a0 = fmaf(w6.x,x6.x,a0); a1 = fmaf(w6.y,x6.y,a1);
        a2 = fmaf(w6.z,x6.z,a2); a3 = fmaf(w6.w,x6.w,a3);
        a0 = fmaf(w7.x,x7.x,a0); a1 = fmaf(w7.y,x7.y,a1);
        a2 = fmaf(w7.z,x7.z,a2); a3 = fmaf(w7.w,x7.w,a3);
        sp[p*192 + row] = (a0+a1)+(a2+a3);
      }
      __syncthreads();
      if (wv == 6) {
        float mr = sp[lane]     + sp[192+lane];
        float mz = sp[64+lane]  + sp[256+lane];
        float mn = sp[128+lane] + sp[320+lane];
        float rg = fsigmoid_(ga[i]  + br + mr);
        float zg = fsigmoid_(gz_[i] + bz + mz);
        float ng = ftanh_(gn_[i] + rg*(bn + mn));
        hu = (1.0f - zg)*ng + zg*hu;
        h[lane] = hu;
        hist[i] = hu;
      }
      __syncthreads();
    }
    if (wv == 6) {
      int t0 = c*16;
      #pragma unroll
      for (int i=0;i<16;i++) hb_[(size_t)(t0+i)*64 + lane] = hist[i];
      if (c < 24) {
        int t1 = t0 + 16;
        #pragma unroll
        for (int i=0;i<16;i++) {
          ga[i]  = gib[(size_t)(t1+i)*192 + lane];
          gz_[i] = gib[(size_t)(t1+i)*192 + 64 + lane];
          gn_[i] = gib[(size_t)(t1+i)*192 + 128 + lane];
        }
      }
    }
  }
}

// ------------- post-MLP + all heads, one block per (b,t) -----------------
__global__ void __launch_bounds__(256) k_heads(
    const float* hs, const float* Wpost, const float* bpost,
    const float* Wharm, const float* bharm,
    const float* Wamp, const float* bamp,
    const float* Wnoise, const float* bnoise,
    const float* Wnamp, const float* bnamp,
    const float* WB, const float* bB,
    float* harm, float* nmag, float* fs) {
  int bt = blockIdx.x; int b = bt / Tn, t = bt % Tn;
  __shared__ float h64[64];
  __shared__ float fp[128];
  __shared__ float lg[256];
  __shared__ float red[8];
  int tid = threadIdx.x;
  if (tid < 64) h64[tid] = hs[((size_t)b*Tn+t)*64+tid];
  __syncthreads();
  if (tid < 128) {
    float a = bpost[tid];
    #pragma unroll 8
    for (int i=0;i<64;i++) a += h64[i]*Wpost[i*128+tid];
    fp[tid] = fmaxf(a,0.0f);
  }
  __syncthreads();
  {
    int c = tid >> 7, n = tid & 127;
    float a = bharm[c*128+n];
    const float* w = Wharm + (size_t)c*128*128 + n;
    #pragma unroll 8
    for (int d=0;d<128;d++) a += fp[d]*w[d*128];
    lg[tid] = a;
  }
  __syncthreads();
  if (tid < 2) {
    const float* l = lg + tid*128;
    float mx = l[0];
    for (int n=1;n<128;n++) mx = fmaxf(mx,l[n]);
    float sm = 0.f; for (int n=0;n<128;n++) sm += expf(l[n]-mx);
    red[tid] = mx; red[2+tid] = sm;
    float aa = bamp[tid];
    for (int d=0;d<128;d++) aa += fp[d]*Wamp[tid*128+d];
    red[4+tid] = softplusf_(aa);
    float na = bnamp[tid];
    for (int d=0;d<128;d++) na += fp[d]*Wnamp[tid*128+d];
    red[6+tid] = softplusf_(na);
  } else if (tid == 2) {
    float bb = bB[0];
    for (int d=0;d<128;d++) bb += fp[d]*WB[d];
    atomicAdd(&fs[6+b], sigmoidf_(bb));
  }
  __syncthreads();
  {
    int c = tid >> 7, n = tid & 127;
    float v = expf(lg[tid]-red[c]) / red[2+c] * red[4+c];
    harm[(((size_t)c*Bn + b)*Tn + t)*128 + n] = v;
  }
  for (int o = tid; o < 2*NNn; o += 256) {
    int c = (o < NNn) ? 0 : 1; int n = o - c*NNn;
    float a = bnoise[c*NNn+n];
    const float* w = Wnoise + (size_t)c*128*NNn + n;
    #pragma unroll 8
    for (int d=0;d<128;d++) a += fp[d]*w[(size_t)d*NNn];
    nmag[(((size_t)c*Bn + b)*Tn + t)*NNn + n] = sigmoidf_(a) * red[6+c];
  }
}

// ---- merged harmonic synth (blocks 0..749) + noise shape/iFFT/OLA --------
__global__ void __launch_bounds__(256) k_harmnoise(
    const float* __restrict__ f0, const float* __restrict__ harm,
    const double* __restrict__ P, const float* __restrict__ fs,
    float* __restrict__ sigh,
    const float2* __restrict__ spec, const float* __restrict__ nmag,
    float* __restrict__ ola) {
  __shared__ double rks[128];
  __shared__ float  rkf[128];
  __shared__ float re[1024], im[1024];
  __shared__ float twc[512], tws[512];
  __shared__ float wdw[1024];
  int tid = threadIdx.x;

  if (blockIdx.x < 750) {
    // ----------------------- harmonic branch ---------------------------
    int b = blockIdx.x / 375;
    int s = (blockIdx.x % 375)*256 + tid;
    if (tid < 128) {
      float inhf = fs[6+b]*(1.0f/(float)Tn) * fs[2+b];
      double inh = (double)inhf;
      double kk = (double)(tid+1);
      double r = kk * sqrt(1.0 + inh*kk*kk);
      rks[tid] = r; rkf[tid] = (float)r;
    }
    __syncthreads();
    const float* f = f0 + b*Tn;
    float posf = ((float)s + 0.5f) * (400.0f/96000.0f) - 0.5f;
    posf = fminf(fmaxf(posf, 0.0f), 399.0f);
    int lo = (int)floorf(posf);
    int hi = min(lo+1, 399);
    float fr = posf - (float)lo;
    float f0up = f[lo]*(1.0f-fr) + f[hi]*fr;
    double C;
    if (s < 120) {
      C = (double)(s+1) * (double)f[0];
    } else if (s < 95880) {
      int m = (s-120)/240;
      int q = s - 120 - 240*m;
      double fm = (double)f[m], fm1 = (double)f[m+1];
      double jp = (double)(q+1);
      C = 120.0*((double)f[0] + P[b*Tn+m]) + jp*fm + (fm1-fm)*jp*jp*(1.0/480.0);
    } else {
      C = 120.0*((double)f[0] + P[b*Tn+399]) + (double)(s-95880+1)*(double)f[399];
    }
    double Phi = C * (2.0*DPI/48000.0);
    const float* hLlo = harm + (((size_t)0*Bn + b)*Tn + lo)*128;
    const float* hLhi = harm + (((size_t)0*Bn + b)*Tn + hi)*128;
    const float* hRlo = harm + (((size_t)1*Bn + b)*Tn + lo)*128;
    const float* hRhi = harm + (((size_t)1*Bn + b)*Tn + hi)*128;
    float accL=0.f, accR=0.f;
    for (int k=0;k<128;k++) {
      float finst = f0up * rkf[k];
      if (finst < CUT) {
        double u = rks[k]*Phi * (1.0/(2.0*DPI));
        u -= floor(u);
        float sv = __sinf((float)u * 6.28318530717959f);
        float aL = hLlo[k]*(1.0f-fr) + hLhi[k]*fr;
        float aR = hRlo[k]*(1.0f-fr) + hRhi[k]*fr;
        accL += aL*sv; accR += aR*sv;
      }
    }
    float na = fs[4+b];
    sigh[((size_t)b*2+0)*Sn + s] = accL/na;
    sigh[((size_t)b*2+1)*Sn + s] = accR/na;
    return;
  }

  // ----------------------- noise branch --------------------------------
  int idx = blockIdx.x - 750;
  int sig = idx / TS, t = idx % TS;
  int b = sig >> 1, c = sig & 1;
  for (int q=tid; q<512; q+=256) {
    float ang = (float)(2.0*DPI) * (float)q * (1.0f/1024.0f);
    twc[q] = cosf(ang); tws[q] = sinf(ang);
  }
  for (int i=tid; i<1024; i+=256)
    wdw[i] = 0.5f - 0.5f*cosf((float)(2.0*DPI)*(float)i*(1.0f/1024.0f));
  float f0m = fs[b];
  float pp = ((float)t + 0.5f) * (400.0f/376.0f) - 0.5f;
  pp = fminf(fmaxf(pp,0.0f),399.0f);
  int tlo = (int)floorf(pp); int thi = min(tlo+1, 399); float tfr = pp - (float)tlo;
  const float* nm = nmag + (((size_t)c*Bn + b)*Tn)*NNn;
  const float2* so = spec + ((size_t)sig*TS + t)*NNn;
  for (int k=tid;k<=512;k+=256) {
    float src = (float)k * 46.875f / f0m * (513.0f/128.0f);
    src = fminf(fmaxf(src,0.0f),512.0f);
    int flo = (int)src; int fhi = min(flo+1,512); float ffr = src - (float)flo;
    float vlo = nm[(size_t)tlo*NNn+flo]*(1.0f-tfr) + nm[(size_t)thi*NNn+flo]*tfr;
    float vhi = nm[(size_t)tlo*NNn+fhi]*(1.0f-tfr) + nm[(size_t)thi*NNn+fhi]*tfr;
    float mag = vlo + ffr*(vhi-vlo);
    float2 v = so[k];
    re[k] = v.x*mag; im[k] = v.y*mag;
  }
  __syncthreads();
  for (int k=tid+513; k<1024; k+=256) {
    re[k] = re[1024-k]; im[k] = -im[1024-k];
  }
  __syncthreads();
  for (int i=tid;i<1024;i+=256) {
    int jx = (int)(__brev((unsigned)i)>>22);
    if (i < jx) {
      float a=re[i]; re[i]=re[jx]; re[jx]=a;
      float bb=im[i]; im[i]=im[jx]; im[jx]=bb;
    }
  }
  __syncthreads();
  for (int st=1; st<=10; st++) {
    int half = 1<<(st-1);
    #pragma unroll
    for (int w=0;w<2;w++) {
      int bid = tid + w*256;
      int pos = bid & (half-1);
      int i0 = ((bid >> (st-1)) << st) + pos;
      int i1 = i0 + half;
      int q = pos << (10-st);
      float cr = twc[q], ci = tws[q];
      float xr = re[i1], xi = im[i1];
      float tr = cr*xr - ci*xi, ti = cr*xi + ci*xr;
      float ar = re[i0], ai = im[i0];
      re[i1] = ar - tr; im[i1] = ai - ti;
      re[i0] = ar + tr; im[i0] = ai + ti;
    }
    __syncthreads();
  }
  float* olab = ola + (size_t)sig*LPn;
  for (int i=tid;i<1024;i+=256) {
    float y = re[i] * (1.0f/1024.0f) * wdw[i];
    atomicAdd(&olab[t*HOPs + i], y);
  }
}

// ------------- final: (harm + ola/wsq) * loudness ------------------------
__global__ void __launch_bounds__(256) k_final(
    const float* loud, const float* sigh, const float* ola, float* out) {
  int b = blockIdx.y;
  int s = blockIdx.x*256 + threadIdx.x;
  float posf = ((float)s + 0.5f)*(400.0f/96000.0f) - 0.5f;
  posf = fminf(fmaxf(posf,0.0f),399.0f);
  int lo=(int)floorf(posf); int hi=min(lo+1,399); float fr=posf-(float)lo;
  const float* ld = loud + b*Tn;
  float lv = exp10f(ld[lo]*0.05f)*(1.0f-fr) + exp10f(ld[hi]*0.05f)*fr;
  int p = PADs + s;
  float wsq;
  if (s >= 511 && s <= 95743) {
    wsq = 1.5f;   // 75%-overlap periodic-Hann^2 COLA constant (interior)
  } else {
    int t0 = (p >= 1023) ? ((p - 1023 + 255) >> 8) : 0;
    int t1 = min(TS-1, p >> 8);
    wsq = 0.0f;
    for (int t=t0;t<=t1;t++) {
      int i = p - (t<<8);
      float w = 0.5f - 0.5f*cosf((float)(2.0*DPI)*(float)i*(1.0f/1024.0f));
      wsq += w*w;
    }
  }
  float denom = (wsq > 1e-11f) ? wsq : 1.0f;
  for (int c=0;c<2;c++) {
    float hv = sigh[((size_t)b*2+c)*Sn+s];
    float nv = ola[(size_t)(b*2+c)*LPn + p] / denom;
    out[((size_t)b*2+c)*Sn + s] = (hv + nv)*lv;
  }
}

extern "C" void kernel_launch(void* const* d_in, const int* in_sizes, int n_in,
                              void* d_out, int out_size, void* d_ws, size_t ws_size,
                              hipStream_t stream) {
  const float* f0    = (const float*)d_in[0];
  const float* loud  = (const float*)d_in[1];
  const float* nL    = (const float*)d_in[2];
  const float* nR    = (const float*)d_in[3];
  const float* Wp1   = (const float*)d_in[4];  const float* bp1 = (const float*)d_in[5];
  const float* Wp2   = (const float*)d_in[6];  const float* bp2 = (const float*)d_in[7];
  const float* Wih   = (const float*)d_in[8];  const float* Whh = (const float*)d_in[9];
  const float* bih   = (const float*)d_in[10]; const float* bhh = (const float*)d_in[11];
  const float* Wpost = (const float*)d_in[12]; const float* bpost=(const float*)d_in[13];
  const float* Wharm = (const float*)d_in[14]; const float* bharm=(const float*)d_in[15];
  const float* Wamp  = (const float*)d_in[16]; const float* bamp =(const float*)d_in[17];
  const float* Wnoise= (const float*)d_in[18]; const float* bnoise=(const float*)d_in[19];
  const float* Wnamp = (const float*)d_in[20]; const float* bnamp=(const float*)d_in[21];
  const float* WB    = (const float*)d_in[22]; const float* bB  = (const float*)d_in[23];
  const int*   vel   = (const int*)d_in[24];
  float* out = (float*)d_out;

  char* w = (char*)d_ws;
  double* P    = (double*)w; w += (size_t)Bn*Tn*sizeof(double);
  double* rk   = (double*)w; w += (size_t)Bn*128*sizeof(double); // layout keep
  float* gi    = (float*)w;  w += (size_t)Bn*Tn*192*sizeof(float);
  float* hsb   = (float*)w;  w += (size_t)Bn*Tn*64*sizeof(float);
  float* harm  = (float*)w;  w += (size_t)2*Bn*Tn*128*sizeof(float);
  float* nmag  = (float*)w;  w += (size_t)2*Bn*Tn*NNn*sizeof(float);
  float* sigh  = (float*)w;  w += (size_t)Bn*2*Sn*sizeof(float);
  float* ola   = (float*)w;  w += (size_t)Bn*2*LPn*sizeof(float);
  float* fscal = (float*)w;  w += 32*sizeof(float);
  float2* spec = (float2*)w; w += (size_t)4*TS*NNn*sizeof(float2);
  (void)rk;

  int nzblk = (97024 + 511) / 512;  // 190 zero-blocks
  k_frame1z<<<Bn*Tn + 1 + nzblk, 128, 0, stream>>>(
      f0, vel, Wp1,bp1, Wp2,bp2, Wih,bih, gi, (float4*)ola, fscal, P);
  k_grufft<<<2 + 4*TS, 448, 0, stream>>>(gi, Whh, bhh, hsb, nL, nR, spec);
  k_heads<<<Bn*Tn, 256, 0, stream>>>(hsb, Wpost,bpost, Wharm,bharm, Wamp,bamp,
                                     Wnoise,bnoise, Wnamp,bnamp, WB,bB,
                                     harm, nmag, fscal);
  k_harmnoise<<<750 + 4*TS, 256, 0, stream>>>(f0, harm, P, fscal, sigh,
                                              spec, nmag, ola);
  dim3 gf(Sn/256, Bn);
  k_final<<<gf, 256, 0, stream>>>(loud, sigh, ola, out);
}

// Round 11
// 386.715 us; speedup vs baseline: 1.0315x; 1.0315x over previous
//
#include <hip/hip_runtime.h>
#include <math.h>

#define Tn   400
#define Bn   2
#define Sn   96000
#define NHh  128
#define NNn  513
#define NFFT 1024
#define HOPs 256
#define PADs 512
#define TS   376      // 1 + Sn/HOPs
#define LPn  97024    // NFFT + (TS-1)*HOPs
#define CUT  21600.0f // SR*0.45
#define DPI  3.14159265358979323846

__device__ __forceinline__ float sigmoidf_(float x){ return 1.0f/(1.0f+expf(-x)); }
__device__ __forceinline__ float softplusf_(float x){ return fmaxf(x,0.0f)+log1pf(expf(-fabsf(x))); }
__device__ __forceinline__ float fsigmoid_(float x){ return __fdividef(1.0f, 1.0f + __expf(-x)); }
__device__ __forceinline__ float ftanh_(float x){
  float e = __expf(fminf(fmaxf(2.0f*x, -30.0f), 30.0f));
  return __fdividef(e - 1.0f, e + 1.0f);
}

// ---- frame-rate MLP (blocks 0..799) + setup (block 800) + ola zero -------
__global__ void __launch_bounds__(128) k_frame1z(
    const float* f0, const int* vel,
    const float* Wp1, const float* bp1,
    const float* Wp2, const float* bp2,
    const float* Wih, const float* bih,
    float* gi, float4* olaz, float* fs, double* P) {
  int blk = blockIdx.x;
  int tid = threadIdx.x;
  if (blk >= Bn*Tn) {
    if (blk == Bn*Tn) {
      int b = tid;
      if (b < Bn) {
        const float* f = f0 + b*Tn;
        double sm = 0.0;
        for (int t=0;t<Tn;t++) sm += fmax((double)f[t], 20.0);
        float f0m = (float)(sm / (double)Tn);
        fs[b] = f0m;
        float midi = 69.0f + 12.0f * log2f(f0m/440.0f);
        fs[2+b] = 0.0008f * expf(-(midi-21.0f)*(1.0f/88.0f) * 2.302585093f);
        double* Pb = P + b*Tn;
        double acc = 0.0;
        for (int m=0;m<Tn;m++){ Pb[m] = acc; if (m < Tn-1) acc += (double)f[m] + (double)f[m+1]; }
        double Ctot = 120.0*((double)f[0] + Pb[Tn-1] + (double)f[Tn-1]);
        double fupmean = Ctot / (double)Sn;
        int cnt = 0;
        for (int k=1;k<=NHh;k++) if ((float)k * (float)fupmean < CUT) cnt++;
        if (cnt < 1) cnt = 1;
        fs[4+b] = (float)cnt;
        fs[6+b] = 0.0f;            // atomic accumulator for k_heads
      }
    } else {
      int base = (blk - (Bn*Tn+1))*512 + tid;
      #pragma unroll
      for (int r=0;r<4;r++) {
        int idx = base + r*128;
        if (idx < 97024) olaz[idx] = make_float4(0.f,0.f,0.f,0.f);
      }
    }
    return;
  }
  int b = blk / Tn, t = blk % Tn;
  __shared__ float x[72];
  __shared__ float y1[128];
  __shared__ float y2[128];
  if (tid < 72) {
    if (tid < 64) {
      float fv = f0[b*Tn+t];
      float fsv = fmaxf(fv, 20.0f);
      float fn = (logf(fsv) - 2.99573227355399f) * (1.0f/5.52146091786225f);
      fn = fminf(fmaxf(fn,0.0f),1.0f);
      int j = (tid>>1) + 1;
      float ang = (float)DPI * (float)j * fn;
      x[tid] = (tid & 1) ? cosf(ang) : sinf(ang);
    } else {
      int i = tid - 64;
      float vn = fminf(fmaxf((float)vel[b]*(1.0f/7.0f),0.0f),1.0f);
      int j = (i>>1)+1;
      float ang = (float)DPI * (float)j * vn;
      x[tid] = (i & 1) ? cosf(ang) : sinf(ang);
    }
  }
  __syncthreads();
  {
    float a = bp1[tid];
    #pragma unroll 8
    for (int i=0;i<72;i++) a += x[i]*Wp1[i*128+tid];
    y1[tid] = fmaxf(a,0.0f);
  }
  __syncthreads();
  {
    float a = bp2[tid];
    #pragma unroll 8
    for (int i=0;i<128;i++) a += y1[i]*Wp2[i*128+tid];
    y2[tid] = fmaxf(a,0.0f);
  }
  __syncthreads();
  float* gout = gi + ((size_t)b*Tn + t)*192;
  for (int g = tid; g < 192; g += 128) {
    float s = bih[g];
    const float* wr = Wih + g*128;
    #pragma unroll 8
    for (int d=0; d<128; d++) s += y2[d]*wr[d];
    gout[g] = s;
  }
}

// ------ fused GRU (blocks 0,1) + forward noise FFT (blocks 2..1505) -------
// R8-exact 13-wave phase-split (measured best 173.4us, VGPR=40) with ONE
// change: gate-wave gi/hist chunk depth 8 -> 16, halving the amortized
// vmcnt(0) drain at the chunk-boundary barrier (~110 -> ~55 cyc/step).
// R9 isolated the wave-count variable (7 waves REGRESSED to 183us: longer
// per-thread serial matvec chain); R7's redundant-gate single-barrier also
// regressed (226us). 13-wave/2-barrier is the proven local optimum.
__global__ void __launch_bounds__(832, 1) k_grufft(
    const float* __restrict__ gi, const float* __restrict__ Whh,
    const float* __restrict__ bhh, float* __restrict__ hsout,
    const float* __restrict__ noiseL, const float* __restrict__ noiseR,
    float2* __restrict__ spec) {
  __shared__ float h[64];
  __shared__ float sp[768];
  __shared__ float re[1024], im[1024];
  __shared__ float twc[512], tws[512];
  __shared__ float wdw[1024];
  int j = threadIdx.x;

  if (blockIdx.x >= 2) {
    // ---------------- forward FFT branch (256 working threads) ----------
    if (j >= 256) return;
    int idx = blockIdx.x - 2;
    int sig = idx / TS, t = idx % TS;
    int b = sig >> 1, c = sig & 1;
    const float* noise = (c==0 ? noiseL : noiseR) + (size_t)b*Sn;
    int tid = j;
    for (int q=tid; q<512; q+=256) {
      float ang = (float)(2.0*DPI) * (float)q * (1.0f/1024.0f);
      twc[q] = cosf(ang); tws[q] = sinf(ang);
    }
    for (int i=tid; i<1024; i+=256)
      wdw[i] = 0.5f - 0.5f*cosf((float)(2.0*DPI)*(float)i*(1.0f/1024.0f));
    __syncthreads();
    for (int i=tid;i<1024;i+=256) {
      int q = t*HOPs + i - PADs;
      if (q < 0) q = -q;
      if (q >= Sn) q = 2*Sn - 2 - q;
      float v = noise[q]*wdw[i];
      int br = (int)(__brev((unsigned)i) >> 22);
      re[br] = v; im[br] = 0.0f;
    }
    __syncthreads();
    for (int st=1; st<=10; st++) {
      int half = 1<<(st-1);
      #pragma unroll
      for (int w=0;w<2;w++) {
        int bid = tid + w*256;
        int pos = bid & (half-1);
        int i0 = ((bid >> (st-1)) << st) + pos;
        int i1 = i0 + half;
        int q = pos << (10-st);
        float cr = twc[q], ci = -tws[q];
        float xr = re[i1], xi = im[i1];
        float tr = cr*xr - ci*xi, ti = cr*xi + ci*xr;
        float ar = re[i0], ai = im[i0];
        re[i1] = ar - tr; im[i1] = ai - ti;
        re[i0] = ar + tr; im[i0] = ai + ti;
      }
      __syncthreads();
    }
    float2* so = spec + ((size_t)sig*TS + t)*NNn;
    for (int k=tid;k<=512;k+=256) so[k] = make_float2(re[k], im[k]);
    return;
  }

  // ---------------- GRU branch (832 threads, 13 waves) ------------------
  int b = blockIdx.x;
  const float* gib = gi + (size_t)b*Tn*192;
  float* hb_ = hsout + (size_t)b*Tn*64;
  int wv = j >> 6, lane = j & 63;
  int p = wv / 3;
  int row = (wv % 3)*64 + lane;
  float4 w0,w1,w2,w3;
  if (j < 768) {
    const float4* W4 = (const float4*)(Whh + (size_t)row*64 + p*16);
    w0=W4[0]; w1=W4[1]; w2=W4[2]; w3=W4[3];
    if (j < 64) h[j] = 0.0f;
  }
  int u = lane;
  float hu = 0.0f, br=0.f, bz=0.f, bn=0.f;
  float ga[16], gz_[16], gn_[16], hist[16];
  if (j >= 768) {
    br = bhh[u]; bz = bhh[64+u]; bn = bhh[128+u];
    #pragma unroll
    for (int i=0;i<16;i++) {
      ga[i]  = gib[(size_t)i*192 + u];
      gz_[i] = gib[(size_t)i*192 + 64 + u];
      gn_[i] = gib[(size_t)i*192 + 128 + u];
    }
  }
  __syncthreads();

  for (int c=0;c<25;c++) {
    #pragma unroll
    for (int i=0;i<16;i++) {
      if (j < 768) {
        const float4* h4 = (const float4*)h;
        float4 x0=h4[p*4+0], x1=h4[p*4+1], x2=h4[p*4+2], x3=h4[p*4+3];
        float a0,a1,a2,a3;
        a0 = w0.x*x0.x; a1 = w0.y*x0.y; a2 = w0.z*x0.z; a3 = w0.w*x0.w;
        a0 = fmaf(w1.x,x1.x,a0); a1 = fmaf(w1.y,x1.y,a1);
        a2 = fmaf(w1.z,x1.z,a2); a3 = fmaf(w1.w,x1.w,a3);
        a0 = fmaf(w2.x,x2.x,a0); a1 = fmaf(w2.y,x2.y,a1);
        a2 = fmaf(w2.z,x2.z,a2); a3 = fmaf(w2.w,x2.w,a3);
        a0 = fmaf(w3.x,x3.x,a0); a1 = fmaf(w3.y,x3.y,a1);
        a2 = fmaf(w3.z,x3.z,a2); a3 = fmaf(w3.w,x3.w,a3);
        sp[p*192 + row] = (a0+a1)+(a2+a3);
      }
      __syncthreads();
      if (j >= 768) {
        float mr = (sp[u]      + sp[192+u])     + (sp[384+u]     + sp[576+u]);
        float mz = (sp[64+u]   + sp[192+64+u])  + (sp[384+64+u]  + sp[576+64+u]);
        float mn = (sp[128+u]  + sp[192+128+u]) + (sp[384+128+u] + sp[576+128+u]);
        float rg = fsigmoid_(ga[i]  + br + mr);
        float zg = fsigmoid_(gz_[i] + bz + mz);
        float ng = ftanh_(gn_[i] + rg*(bn + mn));
        hu = (1.0f - zg)*ng + zg*hu;
        h[u] = hu;
        hist[i] = hu;
      }
      __syncthreads();
    }
    if (j >= 768) {
      int t0 = c*16;
      #pragma unroll
      for (int i=0;i<16;i++) hb_[(size_t)(t0+i)*64 + u] = hist[i];
      if (c < 24) {
        int t1 = t0 + 16;
        #pragma unroll
        for (int i=0;i<16;i++) {
          ga[i]  = gib[(size_t)(t1+i)*192 + u];
          gz_[i] = gib[(size_t)(t1+i)*192 + 64 + u];
          gn_[i] = gib[(size_t)(t1+i)*192 + 128 + u];
        }
      }
    }
  }
}

// ------------- post-MLP + all heads, one block per (b,t) -----------------
__global__ void __launch_bounds__(256) k_heads(
    const float* hs, const float* Wpost, const float* bpost,
    const float* Wharm, const float* bharm,
    const float* Wamp, const float* bamp,
    const float* Wnoise, const float* bnoise,
    const float* Wnamp, const float* bnamp,
    const float* WB, const float* bB,
    float* harm, float* nmag, float* fs) {
  int bt = blockIdx.x; int b = bt / Tn, t = bt % Tn;
  __shared__ float h64[64];
  __shared__ float fp[128];
  __shared__ float lg[256];
  __shared__ float red[8];
  int tid = threadIdx.x;
  if (tid < 64) h64[tid] = hs[((size_t)b*Tn+t)*64+tid];
  __syncthreads();
  if (tid < 128) {
    float a = bpost[tid];
    #pragma unroll 8
    for (int i=0;i<64;i++) a += h64[i]*Wpost[i*128+tid];
    fp[tid] = fmaxf(a,0.0f);
  }
  __syncthreads();
  {
    int c = tid >> 7, n = tid & 127;
    float a = bharm[c*128+n];
    const float* w = Wharm + (size_t)c*128*128 + n;
    #pragma unroll 8
    for (int d=0;d<128;d++) a += fp[d]*w[d*128];
    lg[tid] = a;
  }
  __syncthreads();
  if (tid < 2) {
    const float* l = lg + tid*128;
    float mx = l[0];
    for (int n=1;n<128;n++) mx = fmaxf(mx,l[n]);
    float sm = 0.f; for (int n=0;n<128;n++) sm += expf(l[n]-mx);
    red[tid] = mx; red[2+tid] = sm;
    float aa = bamp[tid];
    for (int d=0;d<128;d++) aa += fp[d]*Wamp[tid*128+d];
    red[4+tid] = softplusf_(aa);
    float na = bnamp[tid];
    for (int d=0;d<128;d++) na += fp[d]*Wnamp[tid*128+d];
    red[6+tid] = softplusf_(na);
  } else if (tid == 2) {
    float bb = bB[0];
    for (int d=0;d<128;d++) bb += fp[d]*WB[d];
    atomicAdd(&fs[6+b], sigmoidf_(bb));
  }
  __syncthreads();
  {
    int c = tid >> 7, n = tid & 127;
    float v = expf(lg[tid]-red[c]) / red[2+c] * red[4+c];
    harm[(((size_t)c*Bn + b)*Tn + t)*128 + n] = v;
  }
  for (int o = tid; o < 2*NNn; o += 256) {
    int c = (o < NNn) ? 0 : 1; int n = o - c*NNn;
    float a = bnoise[c*NNn+n];
    const float* w = Wnoise + (size_t)c*128*NNn + n;
    #pragma unroll 8
    for (int d=0;d<128;d++) a += fp[d]*w[(size_t)d*NNn];
    nmag[(((size_t)c*Bn + b)*Tn + t)*NNn + n] = sigmoidf_(a) * red[6+c];
  }
}

// ---- merged harmonic synth (blocks 0..749) + noise shape/iFFT/OLA --------
__global__ void __launch_bounds__(256) k_harmnoise(
    const float* __restrict__ f0, const float* __restrict__ harm,
    const double* __restrict__ P, const float* __restrict__ fs,
    float* __restrict__ sigh,
    const float2* __restrict__ spec, const float* __restrict__ nmag,
    float* __restrict__ ola) {
  __shared__ double rks[128];
  __shared__ float  rkf[128];
  __shared__ float re[1024], im[1024];
  __shared__ float twc[512], tws[512];
  __shared__ float wdw[1024];
  int tid = threadIdx.x;

  if (blockIdx.x < 750) {
    // ----------------------- harmonic branch ---------------------------
    int b = blockIdx.x / 375;
    int s = (blockIdx.x % 375)*256 + tid;
    if (tid < 128) {
      float inhf = fs[6+b]*(1.0f/(float)Tn) * fs[2+b];
      double inh = (double)inhf;
      double kk = (double)(tid+1);
      double r = kk * sqrt(1.0 + inh*kk*kk);
      rks[tid] = r; rkf[tid] = (float)r;
    }
    __syncthreads();
    const float* f = f0 + b*Tn;
    float posf = ((float)s + 0.5f) * (400.0f/96000.0f) - 0.5f;
    posf = fminf(fmaxf(posf, 0.0f), 399.0f);
    int lo = (int)floorf(posf);
    int hi = min(lo+1, 399);
    float fr = posf - (float)lo;
    float f0up = f[lo]*(1.0f-fr) + f[hi]*fr;
    double C;
    if (s < 120) {
      C = (double)(s+1) * (double)f[0];
    } else if (s < 95880) {
      int m = (s-120)/240;
      int q = s - 120 - 240*m;
      double fm = (double)f[m], fm1 = (double)f[m+1];
      double jp = (double)(q+1);
      C = 120.0*((double)f[0] + P[b*Tn+m]) + jp*fm + (fm1-fm)*jp*jp*(1.0/480.0);
    } else {
      C = 120.0*((double)f[0] + P[b*Tn+399]) + (double)(s-95880+1)*(double)f[399];
    }
    double Phi = C * (2.0*DPI/48000.0);
    const float* hLlo = harm + (((size_t)0*Bn + b)*Tn + lo)*128;
    const float* hLhi = harm + (((size_t)0*Bn + b)*Tn + hi)*128;
    const float* hRlo = harm + (((size_t)1*Bn + b)*Tn + lo)*128;
    const float* hRhi = harm + (((size_t)1*Bn + b)*Tn + hi)*128;
    float accL=0.f, accR=0.f;
    for (int k=0;k<128;k++) {
      float finst = f0up * rkf[k];
      if (finst < CUT) {
        double u = rks[k]*Phi * (1.0/(2.0*DPI));
        u -= floor(u);
        float sv = __sinf((float)u * 6.28318530717959f);
        float aL = hLlo[k]*(1.0f-fr) + hLhi[k]*fr;
        float aR = hRlo[k]*(1.0f-fr) + hRhi[k]*fr;
        accL += aL*sv; accR += aR*sv;
      }
    }
    float na = fs[4+b];
    sigh[((size_t)b*2+0)*Sn + s] = accL/na;
    sigh[((size_t)b*2+1)*Sn + s] = accR/na;
    return;
  }

  // ----------------------- noise branch --------------------------------
  int idx = blockIdx.x - 750;
  int sig = idx / TS, t = idx % TS;
  int b = sig >> 1, c = sig & 1;
  for (int q=tid; q<512; q+=256) {
    float ang = (float)(2.0*DPI) * (float)q * (1.0f/1024.0f);
    twc[q] = cosf(ang); tws[q] = sinf(ang);
  }
  for (int i=tid; i<1024; i+=256)
    wdw[i] = 0.5f - 0.5f*cosf((float)(2.0*DPI)*(float)i*(1.0f/1024.0f));
  float f0m = fs[b];
  float pp = ((float)t + 0.5f) * (400.0f/376.0f) - 0.5f;
  pp = fminf(fmaxf(pp,0.0f),399.0f);
  int tlo = (int)floorf(pp); int thi = min(tlo+1, 399); float tfr = pp - (float)tlo;
  const float* nm = nmag + (((size_t)c*Bn + b)*Tn)*NNn;
  const float2* so = spec + ((size_t)sig*TS + t)*NNn;
  for (int k=tid;k<=512;k+=256) {
    float src = (float)k * 46.875f / f0m * (513.0f/128.0f);
    src = fminf(fmaxf(src,0.0f),512.0f);
    int flo = (int)src; int fhi = min(flo+1,512); float ffr = src - (float)flo;
    float vlo = nm[(size_t)tlo*NNn+flo]*(1.0f-tfr) + nm[(size_t)thi*NNn+flo]*tfr;
    float vhi = nm[(size_t)tlo*NNn+fhi]*(1.0f-tfr) + nm[(size_t)thi*NNn+fhi]*tfr;
    float mag = vlo + ffr*(vhi-vlo);
    float2 v = so[k];
    re[k] = v.x*mag; im[k] = v.y*mag;
  }
  __syncthreads();
  for (int k=tid+513; k<1024; k+=256) {
    re[k] = re[1024-k]; im[k] = -im[1024-k];
  }
  __syncthreads();
  for (int i=tid;i<1024;i+=256) {
    int jx = (int)(__brev((unsigned)i)>>22);
    if (i < jx) {
      float a=re[i]; re[i]=re[jx]; re[jx]=a;
      float bb=im[i]; im[i]=im[jx]; im[jx]=bb;
    }
  }
  __syncthreads();
  for (int st=1; st<=10; st++) {
    int half = 1<<(st-1);
    #pragma unroll
    for (int w=0;w<2;w++) {
      int bid = tid + w*256;
      int pos = bid & (half-1);
      int i0 = ((bid >> (st-1)) << st) + pos;
      int i1 = i0 + half;
      int q = pos << (10-st);
      float cr = twc[q], ci = tws[q];
      float xr = re[i1], xi = im[i1];
      float tr = cr*xr - ci*xi, ti = cr*xi + ci*xr;
      float ar = re[i0], ai = im[i0];
      re[i1] = ar - tr; im[i1] = ai - ti;
      re[i0] = ar + tr; im[i0] = ai + ti;
    }
    __syncthreads();
  }
  float* olab = ola + (size_t)sig*LPn;
  for (int i=tid;i<1024;i+=256) {
    float y = re[i] * (1.0f/1024.0f) * wdw[i];
    atomicAdd(&olab[t*HOPs + i], y);
  }
}

// ------------- final: (harm + ola/wsq) * loudness ------------------------
__global__ void __launch_bounds__(256) k_final(
    const float* loud, const float* sigh, const float* ola, float* out) {
  int b = blockIdx.y;
  int s = blockIdx.x*256 + threadIdx.x;
  float posf = ((float)s + 0.5f)*(400.0f/96000.0f) - 0.5f;
  posf = fminf(fmaxf(posf,0.0f),399.0f);
  int lo=(int)floorf(posf); int hi=min(lo+1,399); float fr=posf-(float)lo;
  const float* ld = loud + b*Tn;
  float lv = exp10f(ld[lo]*0.05f)*(1.0f-fr) + exp10f(ld[hi]*0.05f)*fr;
  int p = PADs + s;
  float wsq;
  if (s >= 511 && s <= 95743) {
    wsq = 1.5f;   // 75%-overlap periodic-Hann^2 COLA constant (interior)
  } else {
    int t0 = (p >= 1023) ? ((p - 1023 + 255) >> 8) : 0;
    int t1 = min(TS-1, p >> 8);
    wsq = 0.0f;
    for (int t=t0;t<=t1;t++) {
      int i = p - (t<<8);
      float w = 0.5f - 0.5f*cosf((float)(2.0*DPI)*(float)i*(1.0f/1024.0f));
      wsq += w*w;
    }
  }
  float denom = (wsq > 1e-11f) ? wsq : 1.0f;
  for (int c=0;c<2;c++) {
    float hv = sigh[((size_t)b*2+c)*Sn+s];
    float nv = ola[(size_t)(b*2+c)*LPn + p] / denom;
    out[((size_t)b*2+c)*Sn + s] = (hv + nv)*lv;
  }
}

extern "C" void kernel_launch(void* const* d_in, const int* in_sizes, int n_in,
                              void* d_out, int out_size, void* d_ws, size_t ws_size,
                              hipStream_t stream) {
  const float* f0    = (const float*)d_in[0];
  const float* loud  = (const float*)d_in[1];
  const float* nL    = (const float*)d_in[2];
  const float* nR    = (const float*)d_in[3];
  const float* Wp1   = (const float*)d_in[4];  const float* bp1 = (const float*)d_in[5];
  const float* Wp2   = (const float*)d_in[6];  const float* bp2 = (const float*)d_in[7];
  const float* Wih   = (const float*)d_in[8];  const float* Whh = (const float*)d_in[9];
  const float* bih   = (const float*)d_in[10]; const float* bhh = (const float*)d_in[11];
  const float* Wpost = (const float*)d_in[12]; const float* bpost=(const float*)d_in[13];
  const float* Wharm = (const float*)d_in[14]; const float* bharm=(const float*)d_in[15];
  const float* Wamp  = (const float*)d_in[16]; const float* bamp =(const float*)d_in[17];
  const float* Wnoise= (const float*)d_in[18]; const float* bnoise=(const float*)d_in[19];
  const float* Wnamp = (const float*)d_in[20]; const float* bnamp=(const float*)d_in[21];
  const float* WB    = (const float*)d_in[22]; const float* bB  = (const float*)d_in[23];
  const int*   vel   = (const int*)d_in[24];
  float* out = (float*)d_out;

  char* w = (char*)d_ws;
  double* P    = (double*)w; w += (size_t)Bn*Tn*sizeof(double);
  double* rk   = (double*)w; w += (size_t)Bn*128*sizeof(double); // layout keep
  float* gi    = (float*)w;  w += (size_t)Bn*Tn*192*sizeof(float);
  float* hsb   = (float*)w;  w += (size_t)Bn*Tn*64*sizeof(float);
  float* harm  = (float*)w;  w += (size_t)2*Bn*Tn*128*sizeof(float);
  float* nmag  = (float*)w;  w += (size_t)2*Bn*Tn*NNn*sizeof(float);
  float* sigh  = (float*)w;  w += (size_t)Bn*2*Sn*sizeof(float);
  float* ola   = (float*)w;  w += (size_t)Bn*2*LPn*sizeof(float);
  float* fscal = (float*)w;  w += 32*sizeof(float);
  float2* spec = (float2*)w; w += (size_t)4*TS*NNn*sizeof(float2);
  (void)rk;

  int nzblk = (97024 + 511) / 512;  // 190 zero-blocks
  k_frame1z<<<Bn*Tn + 1 + nzblk, 128, 0, stream>>>(
      f0, vel, Wp1,bp1, Wp2,bp2, Wih,bih, gi, (float4*)ola, fscal, P);
  k_grufft<<<2 + 4*TS, 832, 0, stream>>>(gi, Whh, bhh, hsb, nL, nR, spec);
  k_heads<<<Bn*Tn, 256, 0, stream>>>(hsb, Wpost,bpost, Wharm,bharm, Wamp,bamp,
                                     Wnoise,bnoise, Wnamp,bnamp, WB,bB,
                                     harm, nmag, fscal);
  k_harmnoise<<<750 + 4*TS, 256, 0, stream>>>(f0, harm, P, fscal, sigh,
                                              spec, nmag, ola);
  dim3 gf(Sn/256, Bn);
  k_final<<<gf, 256, 0, stream>>>(loud, sigh, ola, out);
}